// Round 13
// baseline (391.545 us; speedup 1.0000x reference)
//
#include <hip/hip_runtime.h>
#include <hip/hip_bf16.h>
#include <math.h>

#define QDIM 64
#define KDIM 2
#define NDIM 32
#define MDIM 64
#define EDIM 256
#define DDIM 1024
#define RDIM 200
#define SDIM 8192
#define GCOUNT (QDIM * KDIM * NDIM)  // 4096 groups

typedef short short8_t __attribute__((ext_vector_type(8)));
typedef float f32x4 __attribute__((ext_vector_type(4)));

// tanh(x) = 1 - 2/(1+e^{2x}); saturates correctly, ~1ulp rcp error.
__device__ __forceinline__ float tanh_c(float x) {
    float e = __expf(2.0f * x);
    return 1.0f - 2.0f * __builtin_amdgcn_rcpf(1.0f + e);
}

__device__ __forceinline__ uint32_t f2bf(float f) {  // fp32 -> bf16 bits (RNE)
    uint32_t u = __float_as_uint(f);
    return (u + 0x7fffu + ((u >> 16) & 1u)) >> 16;
}
__device__ __forceinline__ float bf2f(unsigned short h) {
    return __uint_as_float(((uint32_t)h) << 16);
}

// ---------------- fused prologue ----------------
// [0,2048): copy hs->out   [2048,2176): pack Wn   [2176,2432): gq
// [2432,2496): rel_prob    [2496,3520): nv scan (4 groups/block)
__global__ __launch_bounds__(256) void prologue_kernel(
    const float* __restrict__ hs, float* __restrict__ out,
    const float* __restrict__ Wn, short* __restrict__ wnpk,
    const int* __restrict__ gnn_idx, const float* __restrict__ Wq,
    const float* __restrict__ bq, float* __restrict__ gqo,
    const int* __restrict__ rel_idx, const float* __restrict__ Wc,
    const float* __restrict__ bc, float* __restrict__ rel_prob,
    const float* __restrict__ nodes, int* __restrict__ nvarr) {
    const int b = blockIdx.x, t = threadIdx.x;
    __shared__ float row[DDIM];
    __shared__ float arr[256];

    if (b < 2048) {  // copy 32MB
        const float4* src = (const float4*)hs;
        float4* dst = (float4*)out;
        int i = b * 256 + t;
#pragma unroll
        for (int r = 0; r < 4; ++r) dst[i + r * 524288] = src[i + r * 524288];
    } else if (b < 2176) {  // pack Wn -> bf16 B-fragments
        int tid = (b - 2048) * 256 + t;
        int lane = tid & 63, ks = (tid >> 6) & 7, ntg = tid >> 9;
        int low = lane & 15, hi = lane >> 4;
        short8_t o;
#pragma unroll
        for (int j = 0; j < 8; ++j) {
            int k = ks * 32 + hi * 8 + j;
            int d = ntg * 16 + low;
            o[j] = (short)f2bf(Wn[(size_t)k * DDIM + d]);
        }
        *(short8_t*)(wnpk + (size_t)tid * 8) = o;
    } else if (b < 2432) {  // gq
        int bb = b - 2176;
        int q = bb >> 2, seg = bb & 3;
        const float* src = hs + (size_t)gnn_idx[q] * DDIM;
        for (int i = t; i < DDIM; i += 256) row[i] = src[i];
        __syncthreads();
        int d = seg * 256 + t;
        float a = bq[d];
#pragma unroll 8
        for (int k = 0; k < DDIM; ++k) a += row[k] * Wq[(size_t)k * DDIM + d];
        gqo[(size_t)q * DDIM + d] = tanh_c(a);
    } else if (b < 2496) {  // rel_prob
        int q = b - 2432;
        const float* src = hs + (size_t)rel_idx[q] * DDIM;
        for (int i = t; i < DDIM; i += 256) row[i] = src[i];
        __syncthreads();
        float lg = -INFINITY;
        if (t < RDIM) {
            float a = bc[t];
            for (int k = 0; k < DDIM; ++k) a += row[k] * Wc[(size_t)k * RDIM + t];
            lg = a;
        }
        arr[t] = lg;
        __syncthreads();
        for (int s = 128; s > 0; s >>= 1) {
            if (t < s) arr[t] = fmaxf(arr[t], arr[t + s]);
            __syncthreads();
        }
        float mx = arr[0];
        __syncthreads();
        float ex = (t < RDIM) ? __expf(lg - mx) : 0.0f;
        arr[t] = ex;
        __syncthreads();
        for (int s = 128; s > 0; s >>= 1) {
            if (t < s) arr[t] += arr[t + s];
            __syncthreads();
        }
        float sm = arr[0];
        if (t < RDIM) rel_prob[q * RDIM + t] = ex / sm;
    } else {  // nv scan: wave per group
        int g = (b - 2496) * 4 + (t >> 6);
        int lane = t & 63;
        float f0 = nodes[(size_t)g * (MDIM * EDIM) + (size_t)lane * EDIM];
        unsigned long long mk = __ballot(f0 != 0.0f);
        if (lane == 0) nvarr[g] = __popcll(mk);
    }
}

// ---------------- job packing + cq[q] ----------------
// shapes: 0=(4) 1=(3,1) 2=(2,2) 3=(2,1,1) 4=(1,1,1,1); dummy group id = GCOUNT.
// Heavy shapes first; dead (-1) slots last -> block-uniform early return.
__global__ __launch_bounds__(64) void pack_jobs(const int* __restrict__ nvarr,
                                                const float* __restrict__ bn,
                                                const float* __restrict__ gq,
                                                int4* __restrict__ glist4,
                                                float* __restrict__ cqarr) {
    int q = blockIdx.x, t = threadIdx.x;
    __shared__ int lists[4][64];
    __shared__ int cnt[4];
    // cq[q] = sum_d tanh(bn[d]) * gq[q][d]
    float cp = 0.f;
#pragma unroll
    for (int i = 0; i < 16; ++i) {
        int d = i * 64 + t;
        cp += tanh_c(bn[d]) * gq[(size_t)q * DDIM + d];
    }
#pragma unroll
    for (int off = 32; off > 0; off >>= 1) cp += __shfl_xor(cp, off);
    if (t == 0) cqarr[q] = cp;

    if (t < 4) cnt[t] = 0;
    __syncthreads();
    int g = q * 64 + t;
    int nv = nvarr[g];
    int mt = (nv + 15) >> 4;
    if (mt < 1) mt = 1;
    if (mt > 4) mt = 4;
    int pos = atomicAdd(&cnt[mt - 1], 1);
    lists[mt - 1][pos] = g;
    __syncthreads();
    if (t == 0) {
        int c1 = cnt[0], c2 = cnt[1], c3 = cnt[2], c4 = cnt[3];
        int i1 = 0, i2 = 0, i3 = 0, i4 = 0, j = 0;
        int4* outp = glist4 + q * 64;
        const int D = GCOUNT;
        while (i4 < c4) outp[j++] = make_int4(lists[3][i4++] | (0 << 20), D, D, D);
        while (i3 < c3) {
            int g1 = (i1 < c1) ? lists[0][i1++] : D;
            outp[j++] = make_int4(lists[2][i3++] | (1 << 20), g1, D, D);
        }
        while (i2 + 1 < c2) {
            int a = lists[1][i2++], b2 = lists[1][i2++];
            outp[j++] = make_int4(a | (2 << 20), b2, D, D);
        }
        if (i2 < c2) {
            int a = lists[1][i2++];
            int b2 = (i1 < c1) ? lists[0][i1++] : D;
            int c = (i1 < c1) ? lists[0][i1++] : D;
            outp[j++] = make_int4(a | (3 << 20), b2, c, D);
        }
        while (i1 < c1) {
            int a = lists[0][i1++];
            int b2 = (i1 < c1) ? lists[0][i1++] : D;
            int c = (i1 < c1) ? lists[0][i1++] : D;
            int d2 = (i1 < c1) ? lists[0][i1++] : D;
            outp[j++] = make_int4(a | (4 << 20), b2, c, d2);
        }
        while (j < 64) outp[j++] = make_int4(-1, -1, -1, -1);
    }
}

// ---------------- phase1: 4 INDEPENDENT waves / block; wave = one 4-unit job ----
// Per-group epilogue: masked full-wave reductions over the group's unit range.
template <int U0, int NU>
__device__ __forceinline__ void epi(int g, int q, float (&dacc)[4][4],
                                    short8_t (&af)[4][8], float cq, float* scr,
                                    const float* __restrict__ rel_prob,
                                    const int* __restrict__ prob_idx,
                                    float* __restrict__ gvec, float* __restrict__ gden,
                                    float* __restrict__ gmx, int lane) {
    const int low = lane & 15, hi = lane >> 4;
    constexpr int TAIL = 64 - NU * 16;
    float mx = -INFINITY;
#pragma unroll
    for (int u = U0; u < U0 + NU; ++u)
#pragma unroll
        for (int jj = 0; jj < 4; ++jj) mx = fmaxf(mx, dacc[u][jj]);
    mx = fmaxf(mx, __shfl_xor(mx, 16));
    mx = fmaxf(mx, __shfl_xor(mx, 32));
    if (TAIL > 0) mx = fmaxf(mx, cq);
    float exv[4][4];
    float sm = 0.f;
#pragma unroll
    for (int u = U0; u < U0 + NU; ++u)
#pragma unroll
        for (int jj = 0; jj < 4; ++jj) {
            exv[u][jj] = __expf(dacc[u][jj] - mx);
            sm += exv[u][jj];
        }
    sm += __shfl_xor(sm, 16);
    sm += __shfl_xor(sm, 32);
    float ext = __expf(cq - mx);
    if (TAIL > 0) sm += (float)TAIL * ext;
    float pr = rel_prob[(size_t)q * RDIM + prob_idx[g]];
    float p10 = pr * 10.0f / sm;
#pragma unroll
    for (int u = U0; u < U0 + NU; ++u)
#pragma unroll
        for (int jj = 0; jj < 4; ++jj) exv[u][jj] *= p10;
    float lgvt = ext * p10;
    float gm = -INFINITY;
#pragma unroll
    for (int u = U0; u < U0 + NU; ++u)
#pragma unroll
        for (int jj = 0; jj < 4; ++jj) gm = fmaxf(gm, exv[u][jj]);
    gm = fmaxf(gm, __shfl_xor(gm, 16));
    gm = fmaxf(gm, __shfl_xor(gm, 32));
    if (TAIL > 0) gm = fmaxf(gm, lgvt);
    float elv[4][4];
    float den = 0.f;
#pragma unroll
    for (int u = U0; u < U0 + NU; ++u)
#pragma unroll
        for (int jj = 0; jj < 4; ++jj) {
            elv[u][jj] = __expf(exv[u][jj] - gm);
            den += elv[u][jj];
        }
    den += __shfl_xor(den, 16);
    den += __shfl_xor(den, 32);
    if (TAIL > 0) den += (float)TAIL * __expf(lgvt - gm);
    if (lane == 0) {
        gden[g] = den;
        gmx[g] = gm;
    }
    // lv via wave-private LDS bounce (mask already in mkarr)
    float* lvarr = scr;         // 64
    float* mkarr = scr + 64;    // 64
    float* vb = scr + 128;      // 256
    if (low == 0) {
#pragma unroll
        for (int u = U0; u < U0 + NU; ++u)
#pragma unroll
            for (int jj = 0; jj < 4; ++jj) lvarr[u * 16 + hi * 4 + jj] = elv[u][jj];
    }
    asm volatile("s_waitcnt lgkmcnt(0)" ::: "memory");
    float lvm[4];
#pragma unroll
    for (int u = U0; u < U0 + NU; ++u) lvm[u] = lvarr[u * 16 + low] * mkarr[u * 16 + low];
    // weighted column sum from A fragments
#pragma unroll
    for (int ks = 0; ks < 8; ++ks) {
        float acj[8];
#pragma unroll
        for (int j = 0; j < 8; ++j) acj[j] = 0.f;
#pragma unroll
        for (int u = U0; u < U0 + NU; ++u) {
#pragma unroll
            for (int j = 0; j < 8; ++j)
                acj[j] += bf2f((unsigned short)af[u][ks][j]) * lvm[u];
        }
#pragma unroll
        for (int j = 0; j < 8; ++j) {
            float a = acj[j];
            a += __shfl_xor(a, 1);
            a += __shfl_xor(a, 2);
            a += __shfl_xor(a, 4);
            a += __shfl_xor(a, 8);
            if (low == 0) vb[ks * 32 + hi * 8 + j] = a;  // e = ks*32+hi*8+j
        }
    }
    asm volatile("s_waitcnt lgkmcnt(0)" ::: "memory");
    float4 ov = ((const float4*)vb)[lane];
    *(float4*)(gvec + (size_t)g * EDIM + lane * 4) = ov;
    asm volatile("s_waitcnt lgkmcnt(0)" ::: "memory");  // vb reads done before next epi
}

// per-iter vmem = ONLY the 8 B prefetch loads (operands from LDS pairs) so the
// compiler's counted vmcnt leaves the prefetch batch in flight.
#define STEP(CUR, NXT, NTG)                                                              \
    {                                                                                    \
        int pn_ = (NTG) + 1;                                                             \
        pn_ = pn_ > 63 ? 63 : pn_;                                                       \
        const short8_t* pp_ = bbase + (size_t)pn_ * 512;                                 \
        _Pragma("unroll") for (int ks = 0; ks < 8; ++ks) NXT[ks] = pp_[ks * 64];         \
        float2 pv_ = pairs[(NTG)*16 + low];                                              \
        f32x4 a0 = {0.f, 0.f, 0.f, 0.f}, a1 = a0, a2 = a0, a3 = a0;                      \
        _Pragma("unroll") for (int ks = 0; ks < 8; ++ks) {                               \
            a0 = __builtin_amdgcn_mfma_f32_16x16x32_bf16(af[0][ks], CUR[ks], a0, 0, 0, 0); \
            a1 = __builtin_amdgcn_mfma_f32_16x16x32_bf16(af[1][ks], CUR[ks], a1, 0, 0, 0); \
            a2 = __builtin_amdgcn_mfma_f32_16x16x32_bf16(af[2][ks], CUR[ks], a2, 0, 0, 0); \
            a3 = __builtin_amdgcn_mfma_f32_16x16x32_bf16(af[3][ks], CUR[ks], a3, 0, 0, 0); \
        }                                                                                \
        float bnv_ = pv_.x, gqv_ = pv_.y;                                                \
        _Pragma("unroll") for (int jj = 0; jj < 4; ++jj) {                               \
            dacc[0][jj] += tanh_c(a0[jj] + bnv_) * gqv_;                                 \
            dacc[1][jj] += tanh_c(a1[jj] + bnv_) * gqv_;                                 \
            dacc[2][jj] += tanh_c(a2[jj] + bnv_) * gqv_;                                 \
            dacc[3][jj] += tanh_c(a3[jj] + bnv_) * gqv_;                                 \
        }                                                                                \
    }

__global__ __launch_bounds__(256, 2) void phase1_mfma(
    const float* __restrict__ nodes, const short* __restrict__ wnpk,
    const float* __restrict__ bn, const float* __restrict__ gq,
    const float* __restrict__ rel_prob, const int* __restrict__ prob_idx,
    const int4* __restrict__ glist4, const float* __restrict__ cqarr,
    float* __restrict__ gvec, float* __restrict__ gden, float* __restrict__ gmx) {
    __shared__ float2 pairs[DDIM];     // 8KB, block-shared (same q)
    __shared__ float scr4[4][384];     // 6KB wave-private scratch
    const int tid = threadIdx.x;
    const int w = tid >> 6, lane = tid & 63;
    const int low = lane & 15, hi = lane >> 4;

    // 16 blocks per q; dead slots are at the tail of each q's 64-slot list, so
    // slot (b*4) dead => whole block dead (uniform).
    if (glist4[blockIdx.x * 4].x < 0) return;
    const int q = blockIdx.x >> 4;
    const float cqv = cqarr[q];
    const int4 jb = glist4[blockIdx.x * 4 + w];
    const bool live = jb.x >= 0;
    const int shape = live ? ((jb.x >> 20) & 7) : 0;
    const int gA[4] = {jb.x & 0xFFFF, jb.y, jb.z, jb.w};

    // ---- stage (bn,gq) pairs cooperatively; the ONLY barrier ----
    {
        const float* gqrow = gq + (size_t)q * DDIM;
#pragma unroll
        for (int i = 0; i < 4; ++i) {
            int d = tid + i * 256;
            pairs[d] = make_float2(bn[d], gqrow[d]);
        }
    }
    __syncthreads();
    if (!live) return;  // trailing dead waves exit after staging duty

    // unit -> (group slot, tile): byte = slot | tile<<4
    const unsigned tabs[5] = {0x30201000u, 0x01201000u, 0x11011000u, 0x02011000u,
                              0x03020100u};
    const unsigned tb = tabs[shape];

    // ---- A fragments direct from global (no LDS transit):
    // af[u][ks][j] = bf16(nodes[lg][tile*16 + low][ks*32 + hi*8 + j])
    short8_t af[4][8];
#pragma unroll
    for (int u = 0; u < 4; ++u) {
        int byte_ = (tb >> (u * 8)) & 0xFF;
        int slot = byte_ & 0xF, tile = byte_ >> 4;
        int gs = gA[slot];
        int lg = (gs >= GCOUNT) ? 0 : gs;
        const float* rowp =
            nodes + ((size_t)lg * MDIM + tile * 16 + low) * EDIM + hi * 8;
#pragma unroll
        for (int ks = 0; ks < 8; ++ks) {
            float4 a = *(const float4*)(rowp + ks * 32);
            float4 b = *(const float4*)(rowp + ks * 32 + 4);
            short8_t o;
            o[0] = (short)f2bf(a.x); o[1] = (short)f2bf(a.y);
            o[2] = (short)f2bf(a.z); o[3] = (short)f2bf(a.w);
            o[4] = (short)f2bf(b.x); o[5] = (short)f2bf(b.y);
            o[6] = (short)f2bf(b.z); o[7] = (short)f2bf(b.w);
            af[u][ks] = o;
        }
    }

    // ---- masks into wave scratch (row low of each unit, e=0) ----
    float* scr = scr4[w];
    if (hi == 0) {
#pragma unroll
        for (int u = 0; u < 4; ++u) {
            unsigned short s0 = (unsigned short)af[u][0][0];
            (scr + 64)[u * 16 + low] = ((s0 & 0x7fffu) != 0) ? 1.0f : 0.0f;
        }
    }

    // ---- main loop: 64 d-tiles, B reg double-buffer, NO barriers ----
    float dacc[4][4];
#pragma unroll
    for (int u = 0; u < 4; ++u)
#pragma unroll
        for (int jj = 0; jj < 4; ++jj) dacc[u][jj] = 0.f;
    const short8_t* bbase = (const short8_t*)wnpk + lane;
    short8_t bA[8], bB[8];
#pragma unroll
    for (int ks = 0; ks < 8; ++ks) bA[ks] = bbase[ks * 64];
    for (int it = 0; it < 32; ++it) {
        STEP(bA, bB, 2 * it);
        STEP(bB, bA, 2 * it + 1);
    }

    // ---- in-wave reduce over the 16 low-lanes (d-columns) ----
#pragma unroll
    for (int u = 0; u < 4; ++u)
#pragma unroll
        for (int jj = 0; jj < 4; ++jj) {
            float v = dacc[u][jj];
            v += __shfl_xor(v, 1);
            v += __shfl_xor(v, 2);
            v += __shfl_xor(v, 4);
            v += __shfl_xor(v, 8);
            dacc[u][jj] = v;
        }

    // ---- per-group epilogues by shape (wave-local) ----
    switch (shape) {
        case 0:
            epi<0, 4>(gA[0], q, dacc, af, cqv, scr, rel_prob, prob_idx, gvec, gden, gmx, lane);
            break;
        case 1:
            epi<0, 3>(gA[0], q, dacc, af, cqv, scr, rel_prob, prob_idx, gvec, gden, gmx, lane);
            epi<3, 1>(gA[1], q, dacc, af, cqv, scr, rel_prob, prob_idx, gvec, gden, gmx, lane);
            break;
        case 2:
            epi<0, 2>(gA[0], q, dacc, af, cqv, scr, rel_prob, prob_idx, gvec, gden, gmx, lane);
            epi<2, 2>(gA[1], q, dacc, af, cqv, scr, rel_prob, prob_idx, gvec, gden, gmx, lane);
            break;
        case 3:
            epi<0, 2>(gA[0], q, dacc, af, cqv, scr, rel_prob, prob_idx, gvec, gden, gmx, lane);
            epi<2, 1>(gA[1], q, dacc, af, cqv, scr, rel_prob, prob_idx, gvec, gden, gmx, lane);
            epi<3, 1>(gA[2], q, dacc, af, cqv, scr, rel_prob, prob_idx, gvec, gden, gmx, lane);
            break;
        default:
            epi<0, 1>(gA[0], q, dacc, af, cqv, scr, rel_prob, prob_idx, gvec, gden, gmx, lane);
            if (gA[1] < GCOUNT)
                epi<1, 1>(gA[1], q, dacc, af, cqv, scr, rel_prob, prob_idx, gvec, gden, gmx, lane);
            if (gA[2] < GCOUNT)
                epi<2, 1>(gA[2], q, dacc, af, cqv, scr, rel_prob, prob_idx, gvec, gden, gmx, lane);
            if (gA[3] < GCOUNT)
                epi<3, 1>(gA[3], q, dacc, af, cqv, scr, rel_prob, prob_idx, gvec, gden, gmx, lane);
            break;
    }
}

// ---------------- fused combine + out (per q) ----------------
__global__ __launch_bounds__(256) void combineout_kernel(
    const float* __restrict__ gvec, const float* __restrict__ gden,
    const float* __restrict__ gmx, const float* __restrict__ Wg,
    const float* __restrict__ bg, const int* __restrict__ gnn_idx,
    float* __restrict__ out) {
    int q = blockIdx.x, t = threadIdx.x;
    __shared__ float sgm[2][NDIM], sden[2][NDIM];
    __shared__ float pooled[EDIM];
    if (t < 64) {
        int k = t >> 5, n = t & 31;
        sgm[k][n] = gmx[(q * 2 + k) * NDIM + n];
        sden[k][n] = gden[(q * 2 + k) * NDIM + n];
    }
    __syncthreads();
    float pl = 0.f;
#pragma unroll
    for (int k = 0; k < 2; ++k) {
        float gm = -INFINITY;
        for (int n = 0; n < NDIM; ++n) gm = fmaxf(gm, sgm[k][n]);
        float gs = 0.f;
        for (int n = 0; n < NDIM; ++n) gs += sden[k][n] * __expf(sgm[k][n] - gm);
        float me = 0.f;
        for (int n = 0; n < NDIM; ++n)
            me += gvec[(size_t)((q * 2 + k) * NDIM + n) * EDIM + t] *
                  __expf(sgm[k][n] - gm);
        pl += 0.5f * me / (gs * (float)(NDIM * MDIM));
    }
    pooled[t] = pl;
    __syncthreads();
    float4 a = ((const float4*)bg)[t];
    const float4* Wg4 = (const float4*)Wg;
    for (int e = 0; e < EDIM; ++e) {
        float p = pooled[e];
        float4 w = Wg4[(size_t)e * (DDIM / 4) + t];
        a.x += p * w.x; a.y += p * w.y; a.z += p * w.z; a.w += p * w.w;
    }
    float4* op = (float4*)(out + (size_t)gnn_idx[q] * DDIM);
    float4 cur = op[t];
    cur.x += tanh_c(a.x);
    cur.y += tanh_c(a.y);
    cur.z += tanh_c(a.z);
    cur.w += tanh_c(a.w);
    op[t] = cur;
}

extern "C" void kernel_launch(void* const* d_in, const int* in_sizes, int n_in,
                              void* d_out, int out_size, void* d_ws, size_t ws_size,
                              hipStream_t stream) {
    const float* hs = (const float*)d_in[0];
    const float* nodes = (const float*)d_in[1];
    const int* prob_idx = (const int*)d_in[2];
    const int* gnn_idx = (const int*)d_in[3];
    const int* rel_idx = (const int*)d_in[4];
    const float* Wc = (const float*)d_in[5];
    const float* bc = (const float*)d_in[6];
    const float* Wq = (const float*)d_in[7];
    const float* bq = (const float*)d_in[8];
    const float* Wn = (const float*)d_in[9];
    const float* bn = (const float*)d_in[10];
    const float* Wg = (const float*)d_in[11];
    const float* bg = (const float*)d_in[12];
    float* out = (float*)d_out;
    float* ws = (float*)d_ws;

    // ws layout (floats), 16B-aligned sections:
    // relprob[16384] | gq[65536] | gvec[1048832] | gden[4352] | gmx[4352]
    // | memb[32768] | wnpk(bf16=131072 floats) | nvarr[4096]
    // | glist4[int4 x4096 = 16384 floats] | cqarr[64]
    float* relprob = ws;
    float* gqbuf = ws + 16384;
    float* gvec = gqbuf + 65536;                    // 81920
    float* gdenA = gvec + 1048832;                  // 1130752
    float* gmaxA = gdenA + 4352;                    // 1135104
    float* membuf = gmaxA + 4352;                   // 1139456 (reserved)
    short* wnpk = (short*)(membuf + 32768);         // 1172224
    int* nvarr = (int*)(ws + 1303296);
    int4* glist4 = (int4*)(ws + 1307392);
    float* cqarr = ws + 1323776;

    prologue_kernel<<<3520, 256, 0, stream>>>(hs, out, Wn, wnpk, gnn_idx, Wq, bq,
                                              gqbuf, rel_idx, Wc, bc, relprob,
                                              nodes, nvarr);
    pack_jobs<<<QDIM, 64, 0, stream>>>(nvarr, bn, gqbuf, glist4, cqarr);
    phase1_mfma<<<QDIM * 16, 256, 0, stream>>>(nodes, wnpk, bn, gqbuf, relprob,
                                               prob_idx, glist4, cqarr, gvec, gdenA,
                                               gmaxA);
    combineout_kernel<<<QDIM, 256, 0, stream>>>(gvec, gdenA, gmaxA, Wg, bg, gnn_idx,
                                                out);
}

// Round 14
// 350.426 us; speedup vs baseline: 1.1173x; 1.1173x over previous
//
#include <hip/hip_runtime.h>
#include <hip/hip_bf16.h>
#include <math.h>

#define QDIM 64
#define KDIM 2
#define NDIM 32
#define MDIM 64
#define EDIM 256
#define DDIM 1024
#define RDIM 200
#define SDIM 8192
#define GCOUNT (QDIM * KDIM * NDIM)  // 4096 groups

typedef short short8_t __attribute__((ext_vector_type(8)));
typedef float f32x4 __attribute__((ext_vector_type(4)));

// tanh(x) = 1 - 2/(1+e^{2x}); saturates correctly, ~1ulp rcp error.
__device__ __forceinline__ float tanh_c(float x) {
    float e = __expf(2.0f * x);
    return 1.0f - 2.0f * __builtin_amdgcn_rcpf(1.0f + e);
}

__device__ __forceinline__ uint32_t f2bf(float f) {  // fp32 -> bf16 bits (RNE)
    uint32_t u = __float_as_uint(f);
    return (u + 0x7fffu + ((u >> 16) & 1u)) >> 16;
}
__device__ __forceinline__ float bf2f(unsigned short h) {
    return __uint_as_float(((uint32_t)h) << 16);
}

// ---------------- fused prologue ----------------
// [0,2048): copy hs->out   [2048,2176): pack Wn   [2176,2432): gq
// [2432,2496): rel_prob    [2496,3520): nv scan (4 groups/block)
__global__ __launch_bounds__(256) void prologue_kernel(
    const float* __restrict__ hs, float* __restrict__ out,
    const float* __restrict__ Wn, short* __restrict__ wnpk,
    const int* __restrict__ gnn_idx, const float* __restrict__ Wq,
    const float* __restrict__ bq, float* __restrict__ gqo,
    const int* __restrict__ rel_idx, const float* __restrict__ Wc,
    const float* __restrict__ bc, float* __restrict__ rel_prob,
    const float* __restrict__ nodes, int* __restrict__ nvarr) {
    const int b = blockIdx.x, t = threadIdx.x;
    __shared__ float row[DDIM];
    __shared__ float arr[256];

    if (b < 2048) {  // copy 32MB
        const float4* src = (const float4*)hs;
        float4* dst = (float4*)out;
        int i = b * 256 + t;
#pragma unroll
        for (int r = 0; r < 4; ++r) dst[i + r * 524288] = src[i + r * 524288];
    } else if (b < 2176) {  // pack Wn -> bf16 B-fragments
        int tid = (b - 2048) * 256 + t;
        int lane = tid & 63, ks = (tid >> 6) & 7, ntg = tid >> 9;
        int low = lane & 15, hi = lane >> 4;
        short8_t o;
#pragma unroll
        for (int j = 0; j < 8; ++j) {
            int k = ks * 32 + hi * 8 + j;
            int d = ntg * 16 + low;
            o[j] = (short)f2bf(Wn[(size_t)k * DDIM + d]);
        }
        *(short8_t*)(wnpk + (size_t)tid * 8) = o;
    } else if (b < 2432) {  // gq
        int bb = b - 2176;
        int q = bb >> 2, seg = bb & 3;
        const float* src = hs + (size_t)gnn_idx[q] * DDIM;
        for (int i = t; i < DDIM; i += 256) row[i] = src[i];
        __syncthreads();
        int d = seg * 256 + t;
        float a = bq[d];
#pragma unroll 8
        for (int k = 0; k < DDIM; ++k) a += row[k] * Wq[(size_t)k * DDIM + d];
        gqo[(size_t)q * DDIM + d] = tanh_c(a);
    } else if (b < 2496) {  // rel_prob
        int q = b - 2432;
        const float* src = hs + (size_t)rel_idx[q] * DDIM;
        for (int i = t; i < DDIM; i += 256) row[i] = src[i];
        __syncthreads();
        float lg = -INFINITY;
        if (t < RDIM) {
            float a = bc[t];
            for (int k = 0; k < DDIM; ++k) a += row[k] * Wc[(size_t)k * RDIM + t];
            lg = a;
        }
        arr[t] = lg;
        __syncthreads();
        for (int s = 128; s > 0; s >>= 1) {
            if (t < s) arr[t] = fmaxf(arr[t], arr[t + s]);
            __syncthreads();
        }
        float mx = arr[0];
        __syncthreads();
        float ex = (t < RDIM) ? __expf(lg - mx) : 0.0f;
        arr[t] = ex;
        __syncthreads();
        for (int s = 128; s > 0; s >>= 1) {
            if (t < s) arr[t] += arr[t + s];
            __syncthreads();
        }
        float sm = arr[0];
        if (t < RDIM) rel_prob[q * RDIM + t] = ex / sm;
    } else {  // nv scan: wave per group
        int g = (b - 2496) * 4 + (t >> 6);
        int lane = t & 63;
        float f0 = nodes[(size_t)g * (MDIM * EDIM) + (size_t)lane * EDIM];
        unsigned long long mk = __ballot(f0 != 0.0f);
        if (lane == 0) nvarr[g] = __popcll(mk);
    }
}

// ---------------- job packing + cq[q] ----------------
// shapes: 0=(4) 1=(3,1) 2=(2,2) 3=(2,1,1) 4=(1,1,1,1); dummy group id = GCOUNT.
// Heavy shapes first; dead (-1) slots last.
__global__ __launch_bounds__(64) void pack_jobs(const int* __restrict__ nvarr,
                                                const float* __restrict__ bn,
                                                const float* __restrict__ gq,
                                                int4* __restrict__ glist4,
                                                float* __restrict__ cqarr) {
    int q = blockIdx.x, t = threadIdx.x;
    __shared__ int lists[4][64];
    __shared__ int cnt[4];
    // cq[q] = sum_d tanh(bn[d]) * gq[q][d]
    float cp = 0.f;
#pragma unroll
    for (int i = 0; i < 16; ++i) {
        int d = i * 64 + t;
        cp += tanh_c(bn[d]) * gq[(size_t)q * DDIM + d];
    }
#pragma unroll
    for (int off = 32; off > 0; off >>= 1) cp += __shfl_xor(cp, off);
    if (t == 0) cqarr[q] = cp;

    if (t < 4) cnt[t] = 0;
    __syncthreads();
    int g = q * 64 + t;
    int nv = nvarr[g];
    int mt = (nv + 15) >> 4;
    if (mt < 1) mt = 1;
    if (mt > 4) mt = 4;
    int pos = atomicAdd(&cnt[mt - 1], 1);
    lists[mt - 1][pos] = g;
    __syncthreads();
    if (t == 0) {
        int c1 = cnt[0], c2 = cnt[1], c3 = cnt[2], c4 = cnt[3];
        int i1 = 0, i2 = 0, i3 = 0, i4 = 0, j = 0;
        int4* outp = glist4 + q * 64;
        const int D = GCOUNT;
        while (i4 < c4) outp[j++] = make_int4(lists[3][i4++] | (0 << 20), D, D, D);
        while (i3 < c3) {
            int g1 = (i1 < c1) ? lists[0][i1++] : D;
            outp[j++] = make_int4(lists[2][i3++] | (1 << 20), g1, D, D);
        }
        while (i2 + 1 < c2) {
            int a = lists[1][i2++], b2 = lists[1][i2++];
            outp[j++] = make_int4(a | (2 << 20), b2, D, D);
        }
        if (i2 < c2) {
            int a = lists[1][i2++];
            int b2 = (i1 < c1) ? lists[0][i1++] : D;
            int c = (i1 < c1) ? lists[0][i1++] : D;
            outp[j++] = make_int4(a | (3 << 20), b2, c, D);
        }
        while (i1 < c1) {
            int a = lists[0][i1++];
            int b2 = (i1 < c1) ? lists[0][i1++] : D;
            int c = (i1 < c1) ? lists[0][i1++] : D;
            int d2 = (i1 < c1) ? lists[0][i1++] : D;
            outp[j++] = make_int4(a | (4 << 20), b2, c, d2);
        }
        while (j < 64) outp[j++] = make_int4(-1, -1, -1, -1);
    }
}

// ---------------- phase1: 4 INDEPENDENT waves/block; wave = one 4-unit job ----
// Round-7 wave body verbatim (proven no-spill: LDS-transit A staging -> AGPRs).
template <int U0, int NU>
__device__ __forceinline__ void epi(int g, int q, float (&dacc)[4][4],
                                    short8_t (&af)[4][8], float cq, float* scr,
                                    const float* __restrict__ rel_prob,
                                    const int* __restrict__ prob_idx,
                                    float* __restrict__ gvec, float* __restrict__ gden,
                                    float* __restrict__ gmx, int lane) {
    const int low = lane & 15, hi = lane >> 4;
    constexpr int TAIL = 64 - NU * 16;
    float mx = -INFINITY;
#pragma unroll
    for (int u = U0; u < U0 + NU; ++u)
#pragma unroll
        for (int jj = 0; jj < 4; ++jj) mx = fmaxf(mx, dacc[u][jj]);
    mx = fmaxf(mx, __shfl_xor(mx, 16));
    mx = fmaxf(mx, __shfl_xor(mx, 32));
    if (TAIL > 0) mx = fmaxf(mx, cq);
    float exv[4][4];
    float sm = 0.f;
#pragma unroll
    for (int u = U0; u < U0 + NU; ++u)
#pragma unroll
        for (int jj = 0; jj < 4; ++jj) {
            exv[u][jj] = __expf(dacc[u][jj] - mx);
            sm += exv[u][jj];
        }
    sm += __shfl_xor(sm, 16);
    sm += __shfl_xor(sm, 32);
    float ext = __expf(cq - mx);
    if (TAIL > 0) sm += (float)TAIL * ext;
    float pr = rel_prob[(size_t)q * RDIM + prob_idx[g >= GCOUNT ? 0 : g]];
    float p10 = pr * 10.0f / sm;
#pragma unroll
    for (int u = U0; u < U0 + NU; ++u)
#pragma unroll
        for (int jj = 0; jj < 4; ++jj) exv[u][jj] *= p10;
    float lgvt = ext * p10;
    float gm = -INFINITY;
#pragma unroll
    for (int u = U0; u < U0 + NU; ++u)
#pragma unroll
        for (int jj = 0; jj < 4; ++jj) gm = fmaxf(gm, exv[u][jj]);
    gm = fmaxf(gm, __shfl_xor(gm, 16));
    gm = fmaxf(gm, __shfl_xor(gm, 32));
    if (TAIL > 0) gm = fmaxf(gm, lgvt);
    float elv[4][4];
    float den = 0.f;
#pragma unroll
    for (int u = U0; u < U0 + NU; ++u)
#pragma unroll
        for (int jj = 0; jj < 4; ++jj) {
            elv[u][jj] = __expf(exv[u][jj] - gm);
            den += elv[u][jj];
        }
    den += __shfl_xor(den, 16);
    den += __shfl_xor(den, 32);
    if (TAIL > 0) den += (float)TAIL * __expf(lgvt - gm);
    if (lane == 0) {
        gden[g] = den;
        gmx[g] = gm;
    }
    // lv via wave-private LDS bounce (mask already in mkarr)
    float* lvarr = scr;         // 64
    float* mkarr = scr + 64;    // 64
    float* vb = scr + 128;      // 256
    if (low == 0) {
#pragma unroll
        for (int u = U0; u < U0 + NU; ++u)
#pragma unroll
            for (int jj = 0; jj < 4; ++jj) lvarr[u * 16 + hi * 4 + jj] = elv[u][jj];
    }
    asm volatile("s_waitcnt lgkmcnt(0)" ::: "memory");
    float lvm[4];
#pragma unroll
    for (int u = U0; u < U0 + NU; ++u) lvm[u] = lvarr[u * 16 + low] * mkarr[u * 16 + low];
    // weighted column sum from A fragments
#pragma unroll
    for (int ks = 0; ks < 8; ++ks) {
        float acj[8];
#pragma unroll
        for (int j = 0; j < 8; ++j) acj[j] = 0.f;
#pragma unroll
        for (int u = U0; u < U0 + NU; ++u) {
#pragma unroll
            for (int j = 0; j < 8; ++j)
                acj[j] += bf2f((unsigned short)af[u][ks][j]) * lvm[u];
        }
#pragma unroll
        for (int j = 0; j < 8; ++j) {
            float a = acj[j];
            a += __shfl_xor(a, 1);
            a += __shfl_xor(a, 2);
            a += __shfl_xor(a, 4);
            a += __shfl_xor(a, 8);
            if (low == 0) vb[ks * 32 + hi * 8 + j] = a;  // e = ks*32+hi*8+j
        }
    }
    asm volatile("s_waitcnt lgkmcnt(0)" ::: "memory");
    float4 ov = ((const float4*)vb)[lane];
    *(float4*)(gvec + (size_t)g * EDIM + lane * 4) = ov;
    asm volatile("s_waitcnt lgkmcnt(0)" ::: "memory");  // vb reads done before next epi
}

// per-iter vmem = ONLY the 8 B prefetch loads (operands from wave-private LDS
// pairs) so the compiler's counted vmcnt keeps the prefetch batch in flight.
#define STEP(CUR, NXT, NTG)                                                              \
    {                                                                                    \
        int pn_ = (NTG) + 1;                                                             \
        pn_ = pn_ > 63 ? 63 : pn_;                                                       \
        const short8_t* pp_ = bbase + (size_t)pn_ * 512;                                 \
        _Pragma("unroll") for (int ks = 0; ks < 8; ++ks) NXT[ks] = pp_[ks * 64];         \
        float2 pv_ = pairs[(NTG)*16 + low];                                              \
        f32x4 a0 = {0.f, 0.f, 0.f, 0.f}, a1 = a0, a2 = a0, a3 = a0;                      \
        _Pragma("unroll") for (int ks = 0; ks < 8; ++ks) {                               \
            a0 = __builtin_amdgcn_mfma_f32_16x16x32_bf16(af[0][ks], CUR[ks], a0, 0, 0, 0); \
            a1 = __builtin_amdgcn_mfma_f32_16x16x32_bf16(af[1][ks], CUR[ks], a1, 0, 0, 0); \
            a2 = __builtin_amdgcn_mfma_f32_16x16x32_bf16(af[2][ks], CUR[ks], a2, 0, 0, 0); \
            a3 = __builtin_amdgcn_mfma_f32_16x16x32_bf16(af[3][ks], CUR[ks], a3, 0, 0, 0); \
        }                                                                                \
        float bnv_ = pv_.x, gqv_ = pv_.y;                                                \
        _Pragma("unroll") for (int jj = 0; jj < 4; ++jj) {                               \
            dacc[0][jj] += tanh_c(a0[jj] + bnv_) * gqv_;                                 \
            dacc[1][jj] += tanh_c(a1[jj] + bnv_) * gqv_;                                 \
            dacc[2][jj] += tanh_c(a2[jj] + bnv_) * gqv_;                                 \
            dacc[3][jj] += tanh_c(a3[jj] + bnv_) * gqv_;                                 \
        }                                                                                \
    }

template <int MT_SHAPE>
__device__ __forceinline__ void wave_job(
    char* ldsw, float* scr, int4 jb, int q, const float* __restrict__ nodes,
    const short* __restrict__ wnpk, const float* __restrict__ bn,
    const float* __restrict__ gq, const float* __restrict__ rel_prob,
    const int* __restrict__ prob_idx, float cqv, float* __restrict__ gvec,
    float* __restrict__ gden, float* __restrict__ gmx) {
    const int lane = threadIdx.x & 63;
    const int low = lane & 15, hi = lane >> 4;
    const int gA[4] = {jb.x & 0xFFFF, jb.y, jb.z, jb.w};
    const unsigned tabs[5] = {0x30201000u, 0x01201000u, 0x11011000u, 0x02011000u,
                              0x03020100u};
    const unsigned tb = tabs[MT_SHAPE];

    // ---- stage 4 units through wave-private LDS transit -> A fragments (AGPR) ----
    short8_t af[4][8];
#pragma unroll
    for (int u = 0; u < 4; ++u) {
        int byte_ = (tb >> (u * 8)) & 0xFF;
        int slot = byte_ & 0xF, tile = byte_ >> 4;
        int gs = gA[slot];
        int lg = (gs >= GCOUNT) ? 0 : gs;
        const float4* src =
            (const float4*)(nodes + ((size_t)lg * MDIM + tile * 16) * EDIM);
#pragma unroll
        for (int i = 0; i < 16; ++i) {
            int idx4 = i * 64 + lane;
            float4 v = src[idx4];
            int r = idx4 >> 6, c4 = idx4 & 63;
            int off = (r * 512 + c4 * 8) ^ ((r & 7) << 4);
            uint32_t w0 = f2bf(v.x) | (f2bf(v.y) << 16);
            uint32_t w1 = f2bf(v.z) | (f2bf(v.w) << 16);
            *(uint2*)(ldsw + off) = make_uint2(w0, w1);
        }
        asm volatile("s_waitcnt lgkmcnt(0)" ::: "memory");
#pragma unroll
        for (int ks = 0; ks < 8; ++ks) {
            int off = (low * 512 + ks * 64 + hi * 16) ^ ((low & 7) << 4);
            af[u][ks] = *(const short8_t*)(ldsw + off);
        }
        asm volatile("s_waitcnt lgkmcnt(0)" ::: "memory");
    }

    // ---- masks into wave scratch (row low of each unit, e=0) ----
    if (hi == 0) {
#pragma unroll
        for (int u = 0; u < 4; ++u) {
            unsigned short s0 = (unsigned short)af[u][0][0];
            (scr + 64)[u * 16 + low] = ((s0 & 0x7fffu) != 0) ? 1.0f : 0.0f;
        }
    }

    // ---- stage (bn, gq) pairs into transit (A staging done; wave-private) ----
    {
        const float* gqrow = gq + (size_t)q * DDIM;
        float2* pw = (float2*)ldsw;
#pragma unroll
        for (int i = 0; i < 16; ++i) {
            int d = i * 64 + lane;
            float2 v;
            v.x = bn[d];
            v.y = gqrow[d];
            pw[d] = v;
        }
        asm volatile("s_waitcnt lgkmcnt(0)" ::: "memory");
    }
    const float2* pairs = (const float2*)ldsw;

    // ---- main loop: 64 d-tiles, B reg double-buffer, zero barriers ----
    float dacc[4][4];
#pragma unroll
    for (int u = 0; u < 4; ++u)
#pragma unroll
        for (int jj = 0; jj < 4; ++jj) dacc[u][jj] = 0.f;
    const short8_t* bbase = (const short8_t*)wnpk + lane;
    short8_t bA[8], bB[8];
#pragma unroll
    for (int ks = 0; ks < 8; ++ks) bA[ks] = bbase[ks * 64];
    for (int it = 0; it < 32; ++it) {
        STEP(bA, bB, 2 * it);
        STEP(bB, bA, 2 * it + 1);
    }

    // ---- in-wave reduce over the 16 low-lanes ----
#pragma unroll
    for (int u = 0; u < 4; ++u)
#pragma unroll
        for (int jj = 0; jj < 4; ++jj) {
            float v = dacc[u][jj];
            v += __shfl_xor(v, 1);
            v += __shfl_xor(v, 2);
            v += __shfl_xor(v, 4);
            v += __shfl_xor(v, 8);
            dacc[u][jj] = v;
        }

    // ---- per-group epilogues (wave-local) ----
    if (MT_SHAPE == 0) {
        epi<0, 4>(gA[0], q, dacc, af, cqv, scr, rel_prob, prob_idx, gvec, gden, gmx, lane);
    } else if (MT_SHAPE == 1) {
        epi<0, 3>(gA[0], q, dacc, af, cqv, scr, rel_prob, prob_idx, gvec, gden, gmx, lane);
        epi<3, 1>(gA[1], q, dacc, af, cqv, scr, rel_prob, prob_idx, gvec, gden, gmx, lane);
    } else if (MT_SHAPE == 2) {
        epi<0, 2>(gA[0], q, dacc, af, cqv, scr, rel_prob, prob_idx, gvec, gden, gmx, lane);
        epi<2, 2>(gA[1], q, dacc, af, cqv, scr, rel_prob, prob_idx, gvec, gden, gmx, lane);
    } else if (MT_SHAPE == 3) {
        epi<0, 2>(gA[0], q, dacc, af, cqv, scr, rel_prob, prob_idx, gvec, gden, gmx, lane);
        epi<2, 1>(gA[1], q, dacc, af, cqv, scr, rel_prob, prob_idx, gvec, gden, gmx, lane);
        epi<3, 1>(gA[2], q, dacc, af, cqv, scr, rel_prob, prob_idx, gvec, gden, gmx, lane);
    } else {
        epi<0, 1>(gA[0], q, dacc, af, cqv, scr, rel_prob, prob_idx, gvec, gden, gmx, lane);
        if (gA[1] < GCOUNT)
            epi<1, 1>(gA[1], q, dacc, af, cqv, scr, rel_prob, prob_idx, gvec, gden, gmx, lane);
        if (gA[2] < GCOUNT)
            epi<2, 1>(gA[2], q, dacc, af, cqv, scr, rel_prob, prob_idx, gvec, gden, gmx, lane);
        if (gA[3] < GCOUNT)
            epi<3, 1>(gA[3], q, dacc, af, cqv, scr, rel_prob, prob_idx, gvec, gden, gmx, lane);
    }
}

__global__ __launch_bounds__(256, 2) void phase1_mfma(
    const float* __restrict__ nodes, const short* __restrict__ wnpk,
    const float* __restrict__ bn, const float* __restrict__ gq,
    const float* __restrict__ rel_prob, const int* __restrict__ prob_idx,
    const int4* __restrict__ glist4, const float* __restrict__ cqarr,
    float* __restrict__ gvec, float* __restrict__ gden, float* __restrict__ gmx) {
    __shared__ alignas(16) char transit4[4][8192];
    __shared__ float scr4[4][384];
    const int w = threadIdx.x >> 6;
    // dead slots are at each q's tail; first slot dead => all 4 dead (uniform).
    if (glist4[blockIdx.x * 4].x < 0) return;
    const int4 jb = glist4[blockIdx.x * 4 + w];
    if (jb.x < 0) return;  // wave-dead (wave-uniform branch)
    const int q = blockIdx.x >> 4;  // 16 blocks per q
    const float cqv = cqarr[q];
    const int shape = (jb.x >> 20) & 7;
    char* ldsw = transit4[w];
    float* scr = scr4[w];
    switch (shape) {
        case 0: wave_job<0>(ldsw, scr, jb, q, nodes, wnpk, bn, gq, rel_prob, prob_idx, cqv, gvec, gden, gmx); break;
        case 1: wave_job<1>(ldsw, scr, jb, q, nodes, wnpk, bn, gq, rel_prob, prob_idx, cqv, gvec, gden, gmx); break;
        case 2: wave_job<2>(ldsw, scr, jb, q, nodes, wnpk, bn, gq, rel_prob, prob_idx, cqv, gvec, gden, gmx); break;
        case 3: wave_job<3>(ldsw, scr, jb, q, nodes, wnpk, bn, gq, rel_prob, prob_idx, cqv, gvec, gden, gmx); break;
        default: wave_job<4>(ldsw, scr, jb, q, nodes, wnpk, bn, gq, rel_prob, prob_idx, cqv, gvec, gden, gmx); break;
    }
}

// ---------------- fused combine + out (per q) ----------------
__global__ __launch_bounds__(256) void combineout_kernel(
    const float* __restrict__ gvec, const float* __restrict__ gden,
    const float* __restrict__ gmx, const float* __restrict__ Wg,
    const float* __restrict__ bg, const int* __restrict__ gnn_idx,
    float* __restrict__ out) {
    int q = blockIdx.x, t = threadIdx.x;
    __shared__ float sgm[2][NDIM], sden[2][NDIM];
    __shared__ float pooled[EDIM];
    if (t < 64) {
        int k = t >> 5, n = t & 31;
        sgm[k][n] = gmx[(q * 2 + k) * NDIM + n];
        sden[k][n] = gden[(q * 2 + k) * NDIM + n];
    }
    __syncthreads();
    float pl = 0.f;
#pragma unroll
    for (int k = 0; k < 2; ++k) {
        float gm = -INFINITY;
        for (int n = 0; n < NDIM; ++n) gm = fmaxf(gm, sgm[k][n]);
        float gs = 0.f;
        for (int n = 0; n < NDIM; ++n) gs += sden[k][n] * __expf(sgm[k][n] - gm);
        float me = 0.f;
        for (int n = 0; n < NDIM; ++n)
            me += gvec[(size_t)((q * 2 + k) * NDIM + n) * EDIM + t] *
                  __expf(sgm[k][n] - gm);
        pl += 0.5f * me / (gs * (float)(NDIM * MDIM));
    }
    pooled[t] = pl;
    __syncthreads();
    float4 a = ((const float4*)bg)[t];
    const float4* Wg4 = (const float4*)Wg;
    for (int e = 0; e < EDIM; ++e) {
        float p = pooled[e];
        float4 w = Wg4[(size_t)e * (DDIM / 4) + t];
        a.x += p * w.x; a.y += p * w.y; a.z += p * w.z; a.w += p * w.w;
    }
    float4* op = (float4*)(out + (size_t)gnn_idx[q] * DDIM);
    float4 cur = op[t];
    cur.x += tanh_c(a.x);
    cur.y += tanh_c(a.y);
    cur.z += tanh_c(a.z);
    cur.w += tanh_c(a.w);
    op[t] = cur;
}

extern "C" void kernel_launch(void* const* d_in, const int* in_sizes, int n_in,
                              void* d_out, int out_size, void* d_ws, size_t ws_size,
                              hipStream_t stream) {
    const float* hs = (const float*)d_in[0];
    const float* nodes = (const float*)d_in[1];
    const int* prob_idx = (const int*)d_in[2];
    const int* gnn_idx = (const int*)d_in[3];
    const int* rel_idx = (const int*)d_in[4];
    const float* Wc = (const float*)d_in[5];
    const float* bc = (const float*)d_in[6];
    const float* Wq = (const float*)d_in[7];
    const float* bq = (const float*)d_in[8];
    const float* Wn = (const float*)d_in[9];
    const float* bn = (const float*)d_in[10];
    const float* Wg = (const float*)d_in[11];
    const float* bg = (const float*)d_in[12];
    float* out = (float*)d_out;
    float* ws = (float*)d_ws;

    // ws layout (floats), 16B-aligned sections:
    // relprob[16384] | gq[65536] | gvec[1048832] | gden[4352] | gmx[4352]
    // | memb[32768] | wnpk(bf16=131072 floats) | nvarr[4096]
    // | glist4[int4 x4096 = 16384 floats] | cqarr[64]
    float* relprob = ws;
    float* gqbuf = ws + 16384;
    float* gvec = gqbuf + 65536;                    // 81920
    float* gdenA = gvec + 1048832;                  // 1130752
    float* gmaxA = gdenA + 4352;                    // 1135104
    float* membuf = gmaxA + 4352;                   // 1139456 (reserved)
    short* wnpk = (short*)(membuf + 32768);         // 1172224
    int* nvarr = (int*)(ws + 1303296);
    int4* glist4 = (int4*)(ws + 1307392);
    float* cqarr = ws + 1323776;

    prologue_kernel<<<3520, 256, 0, stream>>>(hs, out, Wn, wnpk, gnn_idx, Wq, bq,
                                              gqbuf, rel_idx, Wc, bc, relprob,
                                              nodes, nvarr);
    pack_jobs<<<QDIM, 64, 0, stream>>>(nvarr, bn, gqbuf, glist4, cqarr);
    phase1_mfma<<<QDIM * 16, 256, 0, stream>>>(nodes, wnpk, bn, gqbuf, relprob,
                                               prob_idx, glist4, cqarr, gvec, gdenA,
                                               gmaxA);
    combineout_kernel<<<QDIM, 256, 0, stream>>>(gvec, gdenA, gmaxA, Wg, bg, gnn_idx,
                                                out);
}

// Round 15
// 266.284 us; speedup vs baseline: 1.4704x; 1.3160x over previous
//
#include <hip/hip_runtime.h>
#include <hip/hip_bf16.h>
#include <math.h>

#define QDIM 64
#define KDIM 2
#define NDIM 32
#define MDIM 64
#define EDIM 256
#define DDIM 1024
#define RDIM 200
#define SDIM 8192
#define GCOUNT (QDIM * KDIM * NDIM)  // 4096 groups

#define GLOBAL_AS __attribute__((address_space(1)))
#define LDS_AS __attribute__((address_space(3)))

typedef short short8_t __attribute__((ext_vector_type(8)));
typedef float f32x4 __attribute__((ext_vector_type(4)));

// tanh(x) = 1 - 2/(1+e^{2x}); saturates correctly, ~1ulp rcp error.
__device__ __forceinline__ float tanh_c(float x) {
    float e = __expf(2.0f * x);
    return 1.0f - 2.0f * __builtin_amdgcn_rcpf(1.0f + e);
}

__device__ __forceinline__ uint32_t f2bf(float f) {  // fp32 -> bf16 bits (RNE)
    uint32_t u = __float_as_uint(f);
    return (u + 0x7fffu + ((u >> 16) & 1u)) >> 16;
}
__device__ __forceinline__ float bf2f(unsigned short h) {
    return __uint_as_float(((uint32_t)h) << 16);
}

// ---------------- fused prologue ----------------
// [0,2048): copy hs->out   [2048,2176): pack Wn   [2176,2432): gq
// [2432,2496): rel_prob    [2496,3520): nv scan (4 groups/block)
__global__ __launch_bounds__(256) void prologue_kernel(
    const float* __restrict__ hs, float* __restrict__ out,
    const float* __restrict__ Wn, short* __restrict__ wnpk,
    const int* __restrict__ gnn_idx, const float* __restrict__ Wq,
    const float* __restrict__ bq, float* __restrict__ gqo,
    const int* __restrict__ rel_idx, const float* __restrict__ Wc,
    const float* __restrict__ bc, float* __restrict__ rel_prob,
    const float* __restrict__ nodes, int* __restrict__ nvarr) {
    const int b = blockIdx.x, t = threadIdx.x;
    __shared__ float row[DDIM];
    __shared__ float arr[256];

    if (b < 2048) {  // copy 32MB
        const float4* src = (const float4*)hs;
        float4* dst = (float4*)out;
        int i = b * 256 + t;
#pragma unroll
        for (int r = 0; r < 4; ++r) dst[i + r * 524288] = src[i + r * 524288];
    } else if (b < 2176) {  // pack Wn -> bf16 B-fragments
        int tid = (b - 2048) * 256 + t;
        int lane = tid & 63, ks = (tid >> 6) & 7, ntg = tid >> 9;
        int low = lane & 15, hi = lane >> 4;
        short8_t o;
#pragma unroll
        for (int j = 0; j < 8; ++j) {
            int k = ks * 32 + hi * 8 + j;
            int d = ntg * 16 + low;
            o[j] = (short)f2bf(Wn[(size_t)k * DDIM + d]);
        }
        *(short8_t*)(wnpk + (size_t)tid * 8) = o;
    } else if (b < 2432) {  // gq
        int bb = b - 2176;
        int q = bb >> 2, seg = bb & 3;
        const float* src = hs + (size_t)gnn_idx[q] * DDIM;
        for (int i = t; i < DDIM; i += 256) row[i] = src[i];
        __syncthreads();
        int d = seg * 256 + t;
        float a = bq[d];
#pragma unroll 8
        for (int k = 0; k < DDIM; ++k) a += row[k] * Wq[(size_t)k * DDIM + d];
        gqo[(size_t)q * DDIM + d] = tanh_c(a);
    } else if (b < 2496) {  // rel_prob
        int q = b - 2432;
        const float* src = hs + (size_t)rel_idx[q] * DDIM;
        for (int i = t; i < DDIM; i += 256) row[i] = src[i];
        __syncthreads();
        float lg = -INFINITY;
        if (t < RDIM) {
            float a = bc[t];
            for (int k = 0; k < DDIM; ++k) a += row[k] * Wc[(size_t)k * RDIM + t];
            lg = a;
        }
        arr[t] = lg;
        __syncthreads();
        for (int s = 128; s > 0; s >>= 1) {
            if (t < s) arr[t] = fmaxf(arr[t], arr[t + s]);
            __syncthreads();
        }
        float mx = arr[0];
        __syncthreads();
        float ex = (t < RDIM) ? __expf(lg - mx) : 0.0f;
        arr[t] = ex;
        __syncthreads();
        for (int s = 128; s > 0; s >>= 1) {
            if (t < s) arr[t] += arr[t + s];
            __syncthreads();
        }
        float sm = arr[0];
        if (t < RDIM) rel_prob[q * RDIM + t] = ex / sm;
    } else {  // nv scan: wave per group
        int g = (b - 2496) * 4 + (t >> 6);
        int lane = t & 63;
        float f0 = nodes[(size_t)g * (MDIM * EDIM) + (size_t)lane * EDIM];
        unsigned long long mk = __ballot(f0 != 0.0f);
        if (lane == 0) nvarr[g] = __popcll(mk);
    }
}

// ---------------- job packing + cq[q] ----------------
// shapes: 0=(4) 1=(3,1) 2=(2,2) 3=(2,1,1) 4=(1,1,1,1); dummy group id = GCOUNT.
__global__ __launch_bounds__(64) void pack_jobs(const int* __restrict__ nvarr,
                                                const float* __restrict__ bn,
                                                const float* __restrict__ gq,
                                                int4* __restrict__ glist4,
                                                float* __restrict__ cqarr) {
    int q = blockIdx.x, t = threadIdx.x;
    __shared__ int lists[4][64];
    __shared__ int cnt[4];
    // cq[q] = sum_d tanh(bn[d]) * gq[q][d]
    float cp = 0.f;
#pragma unroll
    for (int i = 0; i < 16; ++i) {
        int d = i * 64 + t;
        cp += tanh_c(bn[d]) * gq[(size_t)q * DDIM + d];
    }
#pragma unroll
    for (int off = 32; off > 0; off >>= 1) cp += __shfl_xor(cp, off);
    if (t == 0) cqarr[q] = cp;

    if (t < 4) cnt[t] = 0;
    __syncthreads();
    int g = q * 64 + t;
    int nv = nvarr[g];
    int mt = (nv + 15) >> 4;
    if (mt < 1) mt = 1;
    if (mt > 4) mt = 4;
    int pos = atomicAdd(&cnt[mt - 1], 1);
    lists[mt - 1][pos] = g;
    __syncthreads();
    if (t == 0) {
        int c1 = cnt[0], c2 = cnt[1], c3 = cnt[2], c4 = cnt[3];
        int i1 = 0, i2 = 0, i3 = 0, i4 = 0, j = 0;
        int4* outp = glist4 + q * 64;
        const int D = GCOUNT;
        while (i4 < c4) outp[j++] = make_int4(lists[3][i4++] | (0 << 20), D, D, D);
        while (i3 < c3) {
            int g1 = (i1 < c1) ? lists[0][i1++] : D;
            outp[j++] = make_int4(lists[2][i3++] | (1 << 20), g1, D, D);
        }
        while (i2 + 1 < c2) {
            int a = lists[1][i2++], b2 = lists[1][i2++];
            outp[j++] = make_int4(a | (2 << 20), b2, D, D);
        }
        if (i2 < c2) {
            int a = lists[1][i2++];
            int b2 = (i1 < c1) ? lists[0][i1++] : D;
            int c = (i1 < c1) ? lists[0][i1++] : D;
            outp[j++] = make_int4(a | (3 << 20), b2, c, D);
        }
        while (i1 < c1) {
            int a = lists[0][i1++];
            int b2 = (i1 < c1) ? lists[0][i1++] : D;
            int c = (i1 < c1) ? lists[0][i1++] : D;
            int d2 = (i1 < c1) ? lists[0][i1++] : D;
            outp[j++] = make_int4(a | (4 << 20), b2, c, d2);
        }
        while (j < 64) outp[j++] = make_int4(-1, -1, -1, -1);
    }
}

// ---------------- phase1: 4-wave block = 2 jobs; wave owns 2 units ----------------
// B via LDS double-buffer (global_load_lds). __launch_bounds__(256,4) caps the
// unified VGPR+AGPR allocation at 128 -> target 4 waves/SIMD. B reads split in
// ks-halves to shrink transient VGPR pressure.
__global__ __launch_bounds__(256, 4) void phase1_mfma(
    const float* __restrict__ nodes, const short* __restrict__ wnpk,
    const float* __restrict__ bn, const float* __restrict__ gq,
    const float* __restrict__ rel_prob, const int* __restrict__ prob_idx,
    const int4* __restrict__ glist4, const float* __restrict__ cqarr,
    float* __restrict__ gvec, float* __restrict__ gden, float* __restrict__ gmx) {
    // LDS union (34.25 KB):
    // [0,8K)=Bbuf0 / wave0 A-transit   [8K,16K)=Bbuf1 / wave1 A-transit
    // [16K,24K)=pairs / wave2 A-transit [24K,32K)=vecu / wave3 A-transit
    // [32K..] dots_s[128] | lv_s[128] | mk_s[128]
    __shared__ alignas(16) char lds[34304];
    float2* pairs = (float2*)(lds + 16384);
    float(*vecu)[EDIM] = (float(*)[EDIM])(lds + 24576);
    float* dots_s = (float*)(lds + 32768);
    float* lv_s = dots_s + 128;
    float* mk_s = lv_s + 128;

    const int tid = threadIdx.x;
    const int w = tid >> 6, lane = tid & 63;
    const int low = lane & 15, hi = lane >> 4;

    const int4 jb0 = glist4[2 * blockIdx.x];
    const int4 jb1 = glist4[2 * blockIdx.x + 1];
    if (jb0.x < 0 && jb1.x < 0) return;  // whole block dead (uniform)
    const int4 jb = (w < 2) ? jb0 : jb1;
    const bool live = jb.x >= 0;
    const int q = ((jb0.x >= 0 ? jb0.x : jb1.x) & 0xFFFF) >> 6;
    const float cqv = cqarr[q];

    // unit -> (group slot, tile): byte = slot | tile<<4
    const unsigned tabs[5] = {0x30201000u, 0x01201000u, 0x11011000u, 0x02011000u,
                              0x03020100u};
    const int gA[4] = {jb.x & 0xFFFF, jb.y, jb.z, jb.w};
    const unsigned tb = live ? tabs[(jb.x >> 20) & 7] : 0;

    // ---- stage this wave's 2 units through its private transit region ----
    int usrc[2] = {GCOUNT, GCOUNT};
    short8_t af[2][8];
    if (live) {
        char* ldsw = lds + w * 8192;
#pragma unroll
        for (int u2 = 0; u2 < 2; ++u2) {
            int u = (w & 1) * 2 + u2;
            int byte_ = (tb >> (u * 8)) & 0xFF;
            int slot = byte_ & 0xF, tile = byte_ >> 4;
            int gs = gA[slot];
            usrc[u2] = gs;
            int lg = (gs >= GCOUNT) ? 0 : gs;
            const float4* src =
                (const float4*)(nodes + ((size_t)lg * MDIM + tile * 16) * EDIM);
#pragma unroll
            for (int i = 0; i < 16; ++i) {
                int idx4 = i * 64 + lane;
                float4 v = src[idx4];
                int r = idx4 >> 6, c4 = idx4 & 63;
                int off = (r * 512 + c4 * 8) ^ ((r & 7) << 4);
                uint32_t w0 = f2bf(v.x) | (f2bf(v.y) << 16);
                uint32_t w1 = f2bf(v.z) | (f2bf(v.w) << 16);
                *(uint2*)(ldsw + off) = make_uint2(w0, w1);
            }
            asm volatile("s_waitcnt lgkmcnt(0)" ::: "memory");
#pragma unroll
            for (int ks = 0; ks < 8; ++ks) {
                int off = (low * 512 + ks * 64 + hi * 16) ^ ((low & 7) << 4);
                af[u2][ks] = *(const short8_t*)(ldsw + off);
            }
            asm volatile("s_waitcnt lgkmcnt(0)" ::: "memory");
        }
    }
    __syncthreads();  // transit regions free; become Bbuf/pairs/vecu

    // ---- stage (bn,gq) pairs ----
    {
        const float* gqrow = gq + (size_t)q * DDIM;
#pragma unroll
        for (int i = 0; i < 4; ++i) {
            int d = tid + i * 256;
            pairs[d] = make_float2(bn[d], gqrow[d]);
        }
    }
    // B stage: ntg tile = 8KB; 2 async 1KB wave-copies per wave (block covers 8KB)
#define STAGE_B(NT, BUF)                                                            \
    {                                                                               \
        const short* sb_ = wnpk + (size_t)(NT)*4096;                                \
        _Pragma("unroll") for (int c_ = 0; c_ < 2; ++c_) {                          \
            int seg_ = (w * 2 + c_) * 512; /* shorts */                             \
            __builtin_amdgcn_global_load_lds(                                       \
                (const GLOBAL_AS void*)(sb_ + seg_ + lane * 8),                     \
                (LDS_AS void*)(lds + (BUF)*8192 + seg_ * 2), 16, 0, 0);             \
        }                                                                           \
    }
    STAGE_B(0, 0);
    asm volatile("s_waitcnt vmcnt(0)" ::: "memory");
    __syncthreads();

    // ---- main loop: 64 d-tiles, LDS B double-buffer, prefetch depth 1 ----
    float dacc[2][4] = {};
    for (int it = 0; it < 64; ++it) {
        const int cur = it & 1;
        if (it < 63) STAGE_B(it + 1, cur ^ 1);
        if (live) {
            const short8_t* bp = (const short8_t*)(lds + cur * 8192) + lane;
            float2 pv = pairs[it * 16 + low];
            f32x4 a0 = {0.f, 0.f, 0.f, 0.f}, a1 = a0;
            // ks-halves: only 4 B-fragments (16 VGPR) live at a time
#pragma unroll
            for (int h = 0; h < 2; ++h) {
                short8_t bf[4];
#pragma unroll
                for (int ks = 0; ks < 4; ++ks) bf[ks] = bp[(h * 4 + ks) * 64];
#pragma unroll
                for (int ks = 0; ks < 4; ++ks) {
                    a0 = __builtin_amdgcn_mfma_f32_16x16x32_bf16(af[0][h * 4 + ks], bf[ks], a0, 0, 0, 0);
                    a1 = __builtin_amdgcn_mfma_f32_16x16x32_bf16(af[1][h * 4 + ks], bf[ks], a1, 0, 0, 0);
                }
            }
            float bnv = pv.x, gqv = pv.y;
#pragma unroll
            for (int jj = 0; jj < 4; ++jj) {
                dacc[0][jj] += tanh_c(a0[jj] + bnv) * gqv;
                dacc[1][jj] += tanh_c(a1[jj] + bnv) * gqv;
            }
        }
        asm volatile("s_waitcnt vmcnt(0)" ::: "memory");
        __syncthreads();
    }

    // ---- in-wave reduce over the 16 low-lanes; publish dots + masks ----
    if (live) {
#pragma unroll
        for (int u2 = 0; u2 < 2; ++u2)
#pragma unroll
            for (int jj = 0; jj < 4; ++jj) {
                float v = dacc[u2][jj];
                v += __shfl_xor(v, 1);
                v += __shfl_xor(v, 2);
                v += __shfl_xor(v, 4);
                v += __shfl_xor(v, 8);
                dacc[u2][jj] = v;
            }
        if (low == 0) {
#pragma unroll
            for (int u2 = 0; u2 < 2; ++u2)
#pragma unroll
                for (int jj = 0; jj < 4; ++jj)
                    dots_s[(w * 2 + u2) * 16 + hi * 4 + jj] = dacc[u2][jj];
        }
        if (hi == 0) {
#pragma unroll
            for (int u2 = 0; u2 < 2; ++u2) {
                unsigned short s0 = (unsigned short)af[u2][0][0];
                mk_s[(w * 2 + u2) * 16 + low] = ((s0 & 0x7fffu) != 0) ? 1.0f : 0.0f;
            }
        }
    }
    __syncthreads();

    // ---- per-group softmax (groups round-robined over waves) ----
    const int NGT[5] = {1, 2, 2, 3, 4};
    const int U0T[5][4] = {{0, 0, 0, 0}, {0, 3, 0, 0}, {0, 2, 0, 0},
                           {0, 2, 3, 0}, {0, 1, 2, 3}};
    const int NUT[5][4] = {{4, 0, 0, 0}, {3, 1, 0, 0}, {2, 2, 0, 0},
                           {2, 1, 1, 0}, {1, 1, 1, 1}};
    const int ng0 = (jb0.x >= 0) ? NGT[(jb0.x >> 20) & 7] : 0;
    const int ng1 = (jb1.x >= 0) ? NGT[(jb1.x >> 20) & 7] : 0;
    const int ngtot = ng0 + ng1;

    for (int gi = w; gi < ngtot; gi += 4) {
        int jx = (gi < ng0) ? 0 : 1;
        int4 J = jx ? jb1 : jb0;
        int li = jx ? gi - ng0 : gi;
        int shp = (J.x >> 20) & 7;
        int U0 = U0T[shp][li] + jx * 4;
        int NU = NUT[shp][li];
        int gg = (li == 0) ? (J.x & 0xFFFF) : (li == 1) ? J.y : (li == 2) ? J.z : J.w;
        if (gg >= GCOUNT) continue;
        int NS = NU * 16, TL = 64 - NS;
        float dv = (lane < NS) ? dots_s[U0 * 16 + lane] : -INFINITY;
        float mx = dv;
#pragma unroll
        for (int o = 32; o > 0; o >>= 1) mx = fmaxf(mx, __shfl_xor(mx, o));
        if (TL > 0) mx = fmaxf(mx, cqv);
        float ex = (lane < NS) ? __expf(dv - mx) : 0.f;
        float sm = ex;
#pragma unroll
        for (int o = 32; o > 0; o >>= 1) sm += __shfl_xor(sm, o);
        float ext = __expf(cqv - mx);
        if (TL > 0) sm += (float)TL * ext;
        float pr = rel_prob[(size_t)q * RDIM + prob_idx[gg]];
        float p10 = pr * 10.0f / sm;
        float l2 = ex * p10;
        float lgvt = ext * p10;
        float gm = (lane < NS) ? l2 : -INFINITY;
#pragma unroll
        for (int o = 32; o > 0; o >>= 1) gm = fmaxf(gm, __shfl_xor(gm, o));
        if (TL > 0) gm = fmaxf(gm, lgvt);
        float el = (lane < NS) ? __expf(l2 - gm) : 0.f;
        float den = el;
#pragma unroll
        for (int o = 32; o > 0; o >>= 1) den += __shfl_xor(den, o);
        if (TL > 0) den += (float)TL * __expf(lgvt - gm);
        if (lane < NS) lv_s[U0 * 16 + lane] = el * mk_s[U0 * 16 + lane];
        if (lane == 0) {
            gden[gg] = den;
            gmx[gg] = gm;
        }
    }
    __syncthreads();

    // ---- per-unit weighted column sums into vecu ----
    if (live) {
#pragma unroll
        for (int u2 = 0; u2 < 2; ++u2) {
            if (usrc[u2] >= GCOUNT) continue;  // dead unit (wave-uniform)
            int ug = w * 2 + u2;
            float lvm = lv_s[ug * 16 + low];
#pragma unroll
            for (int ks = 0; ks < 8; ++ks) {
                float acj[8];
#pragma unroll
                for (int j = 0; j < 8; ++j)
                    acj[j] = bf2f((unsigned short)af[u2][ks][j]) * lvm;
#pragma unroll
                for (int j = 0; j < 8; ++j) {
                    float a = acj[j];
                    a += __shfl_xor(a, 1);
                    a += __shfl_xor(a, 2);
                    a += __shfl_xor(a, 4);
                    a += __shfl_xor(a, 8);
                    acj[j] = a;
                }
                if (low == 0) {
#pragma unroll
                    for (int j = 0; j < 8; ++j) vecu[ug][ks * 32 + hi * 8 + j] = acj[j];
                }
            }
        }
    }
    __syncthreads();

    // ---- owner waves assemble + store gvec rows ----
    for (int gi = w; gi < ngtot; gi += 4) {
        int jx = (gi < ng0) ? 0 : 1;
        int4 J = jx ? jb1 : jb0;
        int li = jx ? gi - ng0 : gi;
        int shp = (J.x >> 20) & 7;
        int U0 = U0T[shp][li] + jx * 4;
        int NU = NUT[shp][li];
        int gg = (li == 0) ? (J.x & 0xFFFF) : (li == 1) ? J.y : (li == 2) ? J.z : J.w;
        if (gg >= GCOUNT) continue;
#pragma unroll 4
        for (int c = 0; c < 4; ++c) {
            int e = c * 64 + lane;
            float s = 0.f;
            for (int uu = 0; uu < NU; ++uu) s += vecu[U0 + uu][e];
            gvec[(size_t)gg * EDIM + e] = s;
        }
    }
}

// ---------------- fused combine + out (per q) ----------------
__global__ __launch_bounds__(256) void combineout_kernel(
    const float* __restrict__ gvec, const float* __restrict__ gden,
    const float* __restrict__ gmx, const float* __restrict__ Wg,
    const float* __restrict__ bg, const int* __restrict__ gnn_idx,
    float* __restrict__ out) {
    int q = blockIdx.x, t = threadIdx.x;
    __shared__ float sgm[2][NDIM], sden[2][NDIM];
    __shared__ float pooled[EDIM];
    if (t < 64) {
        int k = t >> 5, n = t & 31;
        sgm[k][n] = gmx[(q * 2 + k) * NDIM + n];
        sden[k][n] = gden[(q * 2 + k) * NDIM + n];
    }
    __syncthreads();
    float pl = 0.f;
#pragma unroll
    for (int k = 0; k < 2; ++k) {
        float gm = -INFINITY;
        for (int n = 0; n < NDIM; ++n) gm = fmaxf(gm, sgm[k][n]);
        float gs = 0.f;
        for (int n = 0; n < NDIM; ++n) gs += sden[k][n] * __expf(sgm[k][n] - gm);
        float me = 0.f;
        for (int n = 0; n < NDIM; ++n)
            me += gvec[(size_t)((q * 2 + k) * NDIM + n) * EDIM + t] *
                  __expf(sgm[k][n] - gm);
        pl += 0.5f * me / (gs * (float)(NDIM * MDIM));
    }
    pooled[t] = pl;
    __syncthreads();
    float4 a = ((const float4*)bg)[t];
    const float4* Wg4 = (const float4*)Wg;
    for (int e = 0; e < EDIM; ++e) {
        float p = pooled[e];
        float4 w = Wg4[(size_t)e * (DDIM / 4) + t];
        a.x += p * w.x; a.y += p * w.y; a.z += p * w.z; a.w += p * w.w;
    }
    float4* op = (float4*)(out + (size_t)gnn_idx[q] * DDIM);
    float4 cur = op[t];
    cur.x += tanh_c(a.x);
    cur.y += tanh_c(a.y);
    cur.z += tanh_c(a.z);
    cur.w += tanh_c(a.w);
    op[t] = cur;
}

extern "C" void kernel_launch(void* const* d_in, const int* in_sizes, int n_in,
                              void* d_out, int out_size, void* d_ws, size_t ws_size,
                              hipStream_t stream) {
    const float* hs = (const float*)d_in[0];
    const float* nodes = (const float*)d_in[1];
    const int* prob_idx = (const int*)d_in[2];
    const int* gnn_idx = (const int*)d_in[3];
    const int* rel_idx = (const int*)d_in[4];
    const float* Wc = (const float*)d_in[5];
    const float* bc = (const float*)d_in[6];
    const float* Wq = (const float*)d_in[7];
    const float* bq = (const float*)d_in[8];
    const float* Wn = (const float*)d_in[9];
    const float* bn = (const float*)d_in[10];
    const float* Wg = (const float*)d_in[11];
    const float* bg = (const float*)d_in[12];
    float* out = (float*)d_out;
    float* ws = (float*)d_ws;

    // ws layout (floats), 16B-aligned sections:
    // relprob[16384] | gq[65536] | gvec[1048832] | gden[4352] | gmx[4352]
    // | memb[32768] | wnpk(bf16=131072 floats) | nvarr[4096]
    // | glist4[int4 x4096 = 16384 floats] | cqarr[64]
    float* relprob = ws;
    float* gqbuf = ws + 16384;
    float* gvec = gqbuf + 65536;                    // 81920
    float* gdenA = gvec + 1048832;                  // 1130752
    float* gmaxA = gdenA + 4352;                    // 1135104
    float* membuf = gmaxA + 4352;                   // 1139456 (reserved)
    short* wnpk = (short*)(membuf + 32768);         // 1172224
    int* nvarr = (int*)(ws + 1303296);
    int4* glist4 = (int4*)(ws + 1307392);
    float* cqarr = ws + 1323776;

    prologue_kernel<<<3520, 256, 0, stream>>>(hs, out, Wn, wnpk, gnn_idx, Wq, bq,
                                              gqbuf, rel_idx, Wc, bc, relprob,
                                              nodes, nvarr);
    pack_jobs<<<QDIM, 64, 0, stream>>>(nvarr, bn, gqbuf, glist4, cqarr);
    phase1_mfma<<<GCOUNT / 2, 256, 0, stream>>>(nodes, wnpk, bn, gqbuf, relprob,
                                                prob_idx, glist4, cqarr, gvec, gdenA,
                                                gmaxA);
    combineout_kernel<<<QDIM, 256, 0, stream>>>(gvec, gdenA, gmaxA, Wg, bg, gnn_idx,
                                                out);
}